// Round 5
// baseline (293.275 us; speedup 1.0000x reference)
//
#include <hip/hip_runtime.h>
#include <hip/hip_bf16.h>

#define B_ 16
#define C_ 256
#define L_ 2048
#define KVB 32              // m-tile per iteration
#define NT (L_ / KVB)       // 64 tiles

typedef __attribute__((ext_vector_type(8))) short bf16x8;
typedef __attribute__((ext_vector_type(4))) unsigned u32x4;
typedef __attribute__((ext_vector_type(16))) float f32x16;

#define CEXP 0.09016844005556021f   // (1/16) * log2(e), folded into Q conversion

// round-to-nearest-even float -> bf16
__device__ __forceinline__ short f2bf_rne(float f) {
    union { float f; unsigned u; } x; x.f = f;
    unsigned r = x.u + 0x7fffu + ((x.u >> 16) & 1u);
    return (short)(r >> 16);
}

__device__ __forceinline__ unsigned pack2(float lo, float hi) {
    return (unsigned)(unsigned short)f2bf_rne(lo)
         | ((unsigned)(unsigned short)f2bf_rne(hi) << 16);
}

// direct global->LDS DMA, 16 bytes per lane; LDS dest = wave-uniform base + lane*16
__device__ __forceinline__ void gld_lds16(const void* g, void* l) {
    __builtin_amdgcn_global_load_lds(
        (const __attribute__((address_space(1))) void*)g,
        (__attribute__((address_space(3))) void*)l, 16, 0, 0);
}

// ---------------- prepass: K transpose+cvt (blocks 0..511), V*mask cvt (512..4607) ----------
__global__ __launch_bounds__(256) void prepass_kernel(
        const float* __restrict__ Kin, const float* __restrict__ Vin,
        const float* __restrict__ mask,
        short* __restrict__ Kt, short* __restrict__ Vb) {
    const int bid = blockIdx.x;
    const int t = threadIdx.x;
    if (bid < 512) {
        __shared__ unsigned short tile[64 * 256];   // 32 KB, phys chunk = (c>>3) ^ (l&31)
        const int b  = bid >> 5;
        const int l0 = (bid & 31) * 64;
        #pragma unroll
        for (int iter = 0; iter < 16; ++iter) {
            int idx = iter * 256 + t;              // 0..4095
            int ci = idx >> 4;                     // 0..255
            int lc = (idx & 15) * 4;               // l-chunk of 4
            float4 v = *(const float4*)(Kin + ((size_t)(b * C_ + ci)) * L_ + l0 + lc);
            float vv[4] = {v.x, v.y, v.z, v.w};
            #pragma unroll
            for (int j = 0; j < 4; ++j) {
                int l = lc + j;
                tile[l * 256 + (((ci >> 3) ^ (l & 31)) << 3) + (ci & 7)] =
                    (unsigned short)f2bf_rne(vv[j]);
            }
        }
        __syncthreads();
        #pragma unroll
        for (int iter = 0; iter < 8; ++iter) {
            int li = iter * 8 + (t >> 5);          // 0..63
            int ck = t & 31;                       // logical 16-B chunk
            uint4 val = *(const uint4*)(tile + li * 256 + ((ck ^ (li & 31)) << 3));
            *(uint4*)(Kt + ((size_t)(b * L_ + l0 + li)) * C_ + ck * 8) = val;
        }
    } else {
        // 4096 blocks x 256 threads x 8 elems = B_*C_*L_
        size_t e = ((size_t)(bid - 512) * 256 + t) * 8;
        int b = (int)(e >> 19);
        int m = (int)(e & (L_ - 1));
        const float4 v0 = *(const float4*)(Vin + e);
        const float4 v1 = *(const float4*)(Vin + e + 4);
        const float* mp = mask + ((size_t)b << 11) + m;
        const float4 m0 = *(const float4*)mp;
        const float4 m1 = *(const float4*)(mp + 4);
        uint4 o;
        o.x = (unsigned)(unsigned short)f2bf_rne(v0.x * m0.x)
            | ((unsigned)(unsigned short)f2bf_rne(v0.y * m0.y) << 16);
        o.y = (unsigned)(unsigned short)f2bf_rne(v0.z * m0.z)
            | ((unsigned)(unsigned short)f2bf_rne(v0.w * m0.w) << 16);
        o.z = (unsigned)(unsigned short)f2bf_rne(v1.x * m1.x)
            | ((unsigned)(unsigned short)f2bf_rne(v1.y * m1.y) << 16);
        o.w = (unsigned)(unsigned short)f2bf_rne(v1.z * m1.z)
            | ((unsigned)(unsigned short)f2bf_rne(v1.w * m1.w) << 16);
        *(uint4*)(Vb + e) = o;
    }
}

// ---- stage one 32-row K tile via DMA (512 threads x 2 chunks); XOR swizzle on GLOBAL side
// K LDS: [m 0..31][slot p 0..31 of 16B]; phys slot p holds global chunk p ^ m.
__device__ __forceinline__ void stage_K(const short* __restrict__ Ksrc,
                                        short* Ks, int m0, int t) {
    #pragma unroll
    for (int rr = 0; rr < 2; ++rr) {
        int G = rr * 512 + t;                  // 0..1023
        int m = G >> 5, p = G & 31;
        gld_lds16(Ksrc + ((size_t)(m0 + m) << 8) + ((p ^ m) << 3), Ks + G * 8);
    }
}

// ---- stage one V tile (256 c x 32 m bf16 = 16 KB) via DMA (512 threads x 2 chunks) ----
// V LDS: [c 0..255][slot p 0..3 of 16B]; phys slot p holds global chunk p ^ ((c>>1)&3).
// Bank check: quad(lane) = 4*(ln&1) + (w ^ ((ln>>1)&3)) -> bijection per 8 lanes.
__device__ __forceinline__ void stage_V(const short* __restrict__ Vsrc,
                                        short* Vs, int m0, int t) {
    #pragma unroll
    for (int rr = 0; rr < 2; ++rr) {
        int G = rr * 512 + t;                  // 0..1023
        int c = G >> 2, p = G & 3;
        gld_lds16(Vsrc + (size_t)c * L_ + m0 + ((p ^ ((c >> 1) & 3)) << 3), Vs + G * 8);
    }
}

// ---- per-tile body ----
// S' = mfma(A=K, B=Q): lane (ln,h) holds S'[m0 + mr(r,h)][l = lw+ln], mr(r,h)=(r&3)+8(r>>2)+4h.
// softmax lane-local; P redistributed across h-halves via 4 shfl_xor into B-frags b1,b2;
// O = mfma(A=V from LDS, B=P): D[row=c][col=l], 1 contiguous 16-B V chunk per lane per MFMA.
#define TILE_BODY(KS, VS, M0)                                                               \
  {                                                                                         \
    const short* Krow = (KS) + ln * 256;                                                    \
    bf16x8 kf[16];                                                                          \
    _Pragma("unroll")                                                                       \
    for (int ki = 0; ki < 16; ++ki)                                                         \
      kf[ki] = *(const bf16x8*)(Krow + (((2 * ki + h) ^ ln) << 3));                         \
    float4 mk[4];                                                                           \
    _Pragma("unroll")                                                                       \
    for (int s = 0; s < 4; ++s) mk[s] = *(const float4*)(mrow + (M0) + 8 * s + 4 * h);      \
    f32x16 s0 = z16, s1 = z16;                                                              \
    _Pragma("unroll")                                                                       \
    for (int ki = 0; ki < 8; ++ki)                                                          \
      s0 = __builtin_amdgcn_mfma_f32_32x32x16_bf16(kf[ki], qf[ki], s0, 0, 0, 0);            \
    _Pragma("unroll")                                                                       \
    for (int ki = 8; ki < 16; ++ki)                                                         \
      s1 = __builtin_amdgcn_mfma_f32_32x32x16_bf16(kf[ki], qf[ki], s1, 0, 0, 0);            \
    unsigned wds[8];                                                                        \
    _Pragma("unroll")                                                                       \
    for (int u = 0; u < 8; ++u) {                                                           \
      const int ra = 2 * u, rb = 2 * u + 1;                                                 \
      float fa = (mk[ra >> 2][ra & 3] + 1e-9f) * exp2f(s0[ra] + s1[ra]);                    \
      float fb = (mk[rb >> 2][rb & 3] + 1e-9f) * exp2f(s0[rb] + s1[rb]);                    \
      dn += fa + fb;                                                                        \
      wds[u] = pack2(fa, fb);                                                               \
    }                                                                                       \
    unsigned e0 = __shfl_xor(h ? wds[0] : wds[2], 32, 64);                                  \
    unsigned e1 = __shfl_xor(h ? wds[1] : wds[3], 32, 64);                                  \
    unsigned e2 = __shfl_xor(h ? wds[4] : wds[6], 32, 64);                                  \
    unsigned e3 = __shfl_xor(h ? wds[5] : wds[7], 32, 64);                                  \
    u32x4 b1u = { h ? e0 : wds[0], h ? e1 : wds[1], h ? wds[2] : e0, h ? wds[3] : e1 };     \
    u32x4 b2u = { h ? e2 : wds[4], h ? e3 : wds[5], h ? wds[6] : e2, h ? wds[7] : e3 };     \
    bf16x8 b1 = __builtin_bit_cast(bf16x8, b1u);                                            \
    bf16x8 b2 = __builtin_bit_cast(bf16x8, b2u);                                            \
    const int vsw = (ln >> 1) & 3;                                                          \
    _Pragma("unroll")                                                                       \
    for (int ct = 0; ct < 8; ++ct) {                                                        \
      const short* Vrow = (VS) + (32 * ct + ln) * 32;                                       \
      bf16x8 av1 = *(const bf16x8*)(Vrow + ((h ^ vsw) << 3));                               \
      bf16x8 av2 = *(const bf16x8*)(Vrow + (((2 + h) ^ vsw) << 3));                         \
      Oacc[ct] = __builtin_amdgcn_mfma_f32_32x32x16_bf16(av1, b1, Oacc[ct], 0, 0, 0);       \
      Oacc[ct] = __builtin_amdgcn_mfma_f32_32x32x16_bf16(av2, b2, Oacc[ct], 0, 0, 0);       \
    }                                                                                       \
  }

// ------------- main fused attention: 256 blocks x 8 waves, parity m-split -----------------
// b = bid&15, l0 = (bid>>4)*128. Wave pair pr = w>>1 owns l in [l0+32pr, +32); parity e = w&1
// processes tiles with index ≡ e (mod 2). Quad-buffered K/V (phase = tile-pair parity).
// One barrier per 2 tiles; epilogue combines pair partials via LDS.
__global__ __launch_bounds__(512, 2) void attn_main(
        const float* __restrict__ Qin,  // [B][C][L] fp32
        const short* __restrict__ Kt,   // [B][L][C] bf16
        const short* __restrict__ Vb,   // [B][C][L] bf16, mask-scaled
        const float* __restrict__ mask, // [B][L]
        float* __restrict__ out) {      // [B][C][L]
    __shared__ __align__(16) char smem[131584];
    // K phase0: [0,32K)  K phase1: [32K,64K)  V phase0: [64K,96K)  V phase1: [96K,128K)
    // (each phase: parity0 tile at +0, parity1 tile at +16K);  Dsh at 128K (512 B)
    float* Dsh = (float*)(smem + 131072);

    const int t = threadIdx.x;
    const int w = t >> 6, lane = t & 63;
    const int ln = lane & 31, h = lane >> 5;
    const int pr = w >> 1, e = w & 1;

    const int b  = blockIdx.x & 15;
    const int l0 = (blockIdx.x >> 4) * 128;
    const int lw = l0 + 32 * pr;                // wave's l base

    const short* Ksrc = Kt + (size_t)b * (L_ * C_);
    const short* Vsrc = Vb + (size_t)b * (C_ * L_);
    const float* mrow = mask + (size_t)b * L_;

    // this wave's compute buffers (parity-selected, wave-uniform)
    short* KsP0 = (short*)smem + e * 8192;
    short* KsP1 = (short*)(smem + 32768) + e * 8192;
    short* VsP0 = (short*)(smem + 65536) + e * 8192;
    short* VsP1 = (short*)(smem + 98304) + e * 8192;
    // staging targets (all 512 threads cooperate)
    short* KsB[2][2] = { {(short*)smem, (short*)(smem + 16384)},
                         {(short*)(smem + 32768), (short*)(smem + 49152)} };
    short* VsB[2][2] = { {(short*)(smem + 65536), (short*)(smem + 81920)},
                         {(short*)(smem + 98304), (short*)(smem + 114688)} };

    // deep prefetch: tiles 0,1 -> phase 0 (lands during Q gather)
    stage_K(Ksrc, KsB[0][0], 0, t);
    stage_K(Ksrc, KsB[0][1], KVB, t);
    stage_V(Vsrc, VsB[0][0], 0, t);
    stage_V(Vsrc, VsB[0][1], KVB, t);

    // Q B-frags: qf[ki] elem (h,j) = Q[c = 16ki+8h+j][l = lw+ln] * CEXP (one-time gather)
    bf16x8 qf[16];
    {
        const float* Qb = Qin + (size_t)b * (C_ * L_) + (lw + ln);
        #pragma unroll
        for (int ki = 0; ki < 16; ++ki) {
            bf16x8 v;
            #pragma unroll
            for (int j = 0; j < 8; ++j) {
                float f = Qb[(size_t)(16 * ki + 8 * h + j) * L_];
                v[j] = f2bf_rne(f * CEXP);
            }
            qf[ki] = v;
        }
    }

    const f32x16 z16 = {0.f,0.f,0.f,0.f,0.f,0.f,0.f,0.f,0.f,0.f,0.f,0.f,0.f,0.f,0.f,0.f};
    f32x16 Oacc[8];
    #pragma unroll
    for (int ct = 0; ct < 8; ++ct) Oacc[ct] = z16;
    float dn = 0.f;

    __syncthreads();   // phase-0 tiles landed

    #pragma unroll 1
    for (int it4 = 0; it4 < NT / 4; ++it4) {
        const int m0 = it4 * (4 * KVB);

        // phase 0: compute tiles m0 + 32e; stage tiles m0+64, m0+96 -> phase 1
        stage_K(Ksrc, KsB[1][0], m0 + 2 * KVB, t);
        stage_K(Ksrc, KsB[1][1], m0 + 3 * KVB, t);
        stage_V(Vsrc, VsB[1][0], m0 + 2 * KVB, t);
        stage_V(Vsrc, VsB[1][1], m0 + 3 * KVB, t);
        TILE_BODY(KsP0, VsP0, m0 + KVB * e)
        __syncthreads();

        // phase 1: compute tiles m0+64+32e; stage tiles m0+128, m0+160 -> phase 0
        if (it4 + 1 < NT / 4) {
            stage_K(Ksrc, KsB[0][0], m0 + 4 * KVB, t);
            stage_K(Ksrc, KsB[0][1], m0 + 5 * KVB, t);
            stage_V(Vsrc, VsB[0][0], m0 + 4 * KVB, t);
            stage_V(Vsrc, VsB[0][1], m0 + 5 * KVB, t);
        }
        TILE_BODY(KsP1, VsP1, m0 + 2 * KVB + KVB * e)
        __syncthreads();
    }

    // ---- combine pair partials: odd waves dump to LDS (dead K/V space), even waves finish
    dn += __shfl_xor(dn, 32, 64);

    if (e) {
        char* Ob = smem + pr * 32768;
        #pragma unroll
        for (int ct = 0; ct < 8; ++ct)
            #pragma unroll
            for (int rq = 0; rq < 4; ++rq) {
                float4 v4 = { Oacc[ct][4*rq+0], Oacc[ct][4*rq+1],
                              Oacc[ct][4*rq+2], Oacc[ct][4*rq+3] };
                *(float4*)(Ob + lane * 512 + (((ct * 4 + rq) ^ (lane & 31)) << 4)) = v4;
            }
        if (h == 0) Dsh[pr * 32 + ln] = dn;
    }
    __syncthreads();
    if (!e) {
        dn += Dsh[pr * 32 + ln];
        const float rden = 1.0f / dn;
        const char* Ob = smem + pr * 32768;
        float* ob = out + (size_t)b * (C_ * L_) + lw + ln;
        #pragma unroll
        for (int ct = 0; ct < 8; ++ct)
            #pragma unroll
            for (int rq = 0; rq < 4; ++rq) {
                float4 p4 = *(const float4*)(Ob + lane * 512 + (((ct * 4 + rq) ^ (lane & 31)) << 4));
                #pragma unroll
                for (int j = 0; j < 4; ++j) {
                    int r = 4 * rq + j;
                    int c = 32 * ct + (r & 3) + 8 * (r >> 2) + 4 * h;
                    ob[(size_t)c * L_] = (Oacc[ct][r] + ((const float*)&p4)[j]) * rden;
                }
            }
    }
}

extern "C" void kernel_launch(void* const* d_in, const int* in_sizes, int n_in,
                              void* d_out, int out_size, void* d_ws, size_t ws_size,
                              hipStream_t stream) {
    const float* Q    = (const float*)d_in[0];
    const float* K    = (const float*)d_in[1];
    const float* V    = (const float*)d_in[2];
    const float* mask = (const float*)d_in[3];
    float* out = (float*)d_out;

    // workspace: Kt | Vb, each B*L*C bf16 = 16 MiB
    short* Kt = (short*)d_ws;
    short* Vb = Kt + (size_t)B_ * L_ * C_;

    prepass_kernel<<<4608, 256, 0, stream>>>(K, V, mask, Kt, Vb);
    attn_main<<<256, 512, 0, stream>>>(Q, Kt, Vb, mask, out);
}

// Round 6
// 292.605 us; speedup vs baseline: 1.0023x; 1.0023x over previous
//
#include <hip/hip_runtime.h>
#include <hip/hip_bf16.h>

#define B_ 16
#define C_ 256
#define L_ 2048
#define KVB 32              // m-tile per iteration
#define NT (L_ / KVB)       // 64 tiles

typedef __attribute__((ext_vector_type(8))) short bf16x8;
typedef __attribute__((ext_vector_type(4))) unsigned u32x4;
typedef __attribute__((ext_vector_type(16))) float f32x16;

#define CEXP 0.09016844005556021f   // (1/16) * log2(e), folded into Q conversion

// round-to-nearest-even float -> bf16
__device__ __forceinline__ short f2bf_rne(float f) {
    union { float f; unsigned u; } x; x.f = f;
    unsigned r = x.u + 0x7fffu + ((x.u >> 16) & 1u);
    return (short)(r >> 16);
}

__device__ __forceinline__ unsigned pack2(float lo, float hi) {
    return (unsigned)(unsigned short)f2bf_rne(lo)
         | ((unsigned)(unsigned short)f2bf_rne(hi) << 16);
}

// direct global->LDS DMA, 16 bytes per lane; LDS dest = wave-uniform base + lane*16
__device__ __forceinline__ void gld_lds16(const void* g, void* l) {
    __builtin_amdgcn_global_load_lds(
        (const __attribute__((address_space(1))) void*)g,
        (__attribute__((address_space(3))) void*)l, 16, 0, 0);
}

// ---------------- prepass: K transpose+cvt (blocks 0..511), V*mask cvt (512..4607) ----------
__global__ __launch_bounds__(256) void prepass_kernel(
        const float* __restrict__ Kin, const float* __restrict__ Vin,
        const float* __restrict__ mask,
        short* __restrict__ Kt, short* __restrict__ Vb) {
    const int bid = blockIdx.x;
    const int t = threadIdx.x;
    if (bid < 512) {
        __shared__ unsigned short tile[64 * 256];   // 32 KB, phys chunk = (c>>3) ^ (l&31)
        const int b  = bid >> 5;
        const int l0 = (bid & 31) * 64;
        #pragma unroll
        for (int iter = 0; iter < 16; ++iter) {
            int idx = iter * 256 + t;              // 0..4095
            int ci = idx >> 4;                     // 0..255
            int lc = (idx & 15) * 4;               // l-chunk of 4
            float4 v = *(const float4*)(Kin + ((size_t)(b * C_ + ci)) * L_ + l0 + lc);
            float vv[4] = {v.x, v.y, v.z, v.w};
            #pragma unroll
            for (int j = 0; j < 4; ++j) {
                int l = lc + j;
                tile[l * 256 + (((ci >> 3) ^ (l & 31)) << 3) + (ci & 7)] =
                    (unsigned short)f2bf_rne(vv[j]);
            }
        }
        __syncthreads();
        #pragma unroll
        for (int iter = 0; iter < 8; ++iter) {
            int li = iter * 8 + (t >> 5);          // 0..63
            int ck = t & 31;                       // logical 16-B chunk
            uint4 val = *(const uint4*)(tile + li * 256 + ((ck ^ (li & 31)) << 3));
            *(uint4*)(Kt + ((size_t)(b * L_ + l0 + li)) * C_ + ck * 8) = val;
        }
    } else {
        // 4096 blocks x 256 threads x 8 elems = B_*C_*L_
        size_t e = ((size_t)(bid - 512) * 256 + t) * 8;
        int b = (int)(e >> 19);
        int m = (int)(e & (L_ - 1));
        const float4 v0 = *(const float4*)(Vin + e);
        const float4 v1 = *(const float4*)(Vin + e + 4);
        const float* mp = mask + ((size_t)b << 11) + m;
        const float4 m0 = *(const float4*)mp;
        const float4 m1 = *(const float4*)(mp + 4);
        uint4 o;
        o.x = (unsigned)(unsigned short)f2bf_rne(v0.x * m0.x)
            | ((unsigned)(unsigned short)f2bf_rne(v0.y * m0.y) << 16);
        o.y = (unsigned)(unsigned short)f2bf_rne(v0.z * m0.z)
            | ((unsigned)(unsigned short)f2bf_rne(v0.w * m0.w) << 16);
        o.z = (unsigned)(unsigned short)f2bf_rne(v1.x * m1.x)
            | ((unsigned)(unsigned short)f2bf_rne(v1.y * m1.y) << 16);
        o.w = (unsigned)(unsigned short)f2bf_rne(v1.z * m1.z)
            | ((unsigned)(unsigned short)f2bf_rne(v1.w * m1.w) << 16);
        *(uint4*)(Vb + e) = o;
    }
}

// ---- stage one 32-row K tile via DMA (512 threads x 2 chunks); XOR swizzle on GLOBAL side
// K LDS: [m 0..31][slot p 0..31 of 16B]; phys slot p holds global chunk p ^ m.
__device__ __forceinline__ void stage_K(const short* __restrict__ Ksrc,
                                        short* Ks, int m0, int t) {
    #pragma unroll
    for (int rr = 0; rr < 2; ++rr) {
        int G = rr * 512 + t;                  // 0..1023
        int m = G >> 5, p = G & 31;
        gld_lds16(Ksrc + ((size_t)(m0 + m) << 8) + ((p ^ m) << 3), Ks + G * 8);
    }
}

// ---- stage one V tile (256 c x 32 m bf16 = 16 KB) via DMA (512 threads x 2 chunks) ----
// V LDS: [c 0..255][slot p 0..3 of 16B]; phys slot p holds global chunk p ^ ((c>>1)&3).
// Bank check: quad(lane) = 4*(ln&1) + (h ^ ((ln>>1)&3)) -> bijection per 8 lanes.
__device__ __forceinline__ void stage_V(const short* __restrict__ Vsrc,
                                        short* Vs, int m0, int t) {
    #pragma unroll
    for (int rr = 0; rr < 2; ++rr) {
        int G = rr * 512 + t;                  // 0..1023
        int c = G >> 2, p = G & 3;
        gld_lds16(Vsrc + (size_t)c * L_ + m0 + ((p ^ ((c >> 1) & 3)) << 3), Vs + G * 8);
    }
}

// ---- per-tile body ----
// S' = mfma(A=K, B=Q): lane (ln,h) holds S'[m0 + mr(r,h)][l = lw+ln], mr(r,h)=(r&3)+8(r>>2)+4h.
// softmax lane-local; P redistributed across h-halves via 4 shfl_xor into B-frags b1,b2;
// O = mfma(A=V from LDS, B=P): D[row=c][col=l], 1 contiguous 16-B V chunk per lane per MFMA.
#define TILE_BODY(KS, VS, M0)                                                               \
  {                                                                                         \
    const short* Krow = (KS) + ln * 256;                                                    \
    bf16x8 kf[16];                                                                          \
    _Pragma("unroll")                                                                       \
    for (int ki = 0; ki < 16; ++ki)                                                         \
      kf[ki] = *(const bf16x8*)(Krow + (((2 * ki + h) ^ ln) << 3));                         \
    float4 mk[4];                                                                           \
    _Pragma("unroll")                                                                       \
    for (int s = 0; s < 4; ++s) mk[s] = *(const float4*)(mrow + (M0) + 8 * s + 4 * h);      \
    f32x16 s0 = z16, s1 = z16;                                                              \
    _Pragma("unroll")                                                                       \
    for (int ki = 0; ki < 8; ++ki)                                                          \
      s0 = __builtin_amdgcn_mfma_f32_32x32x16_bf16(kf[ki], qf[ki], s0, 0, 0, 0);            \
    _Pragma("unroll")                                                                       \
    for (int ki = 8; ki < 16; ++ki)                                                         \
      s1 = __builtin_amdgcn_mfma_f32_32x32x16_bf16(kf[ki], qf[ki], s1, 0, 0, 0);            \
    unsigned wds[8];                                                                        \
    _Pragma("unroll")                                                                       \
    for (int u = 0; u < 8; ++u) {                                                           \
      const int ra = 2 * u, rb = 2 * u + 1;                                                 \
      float fa = (mk[ra >> 2][ra & 3] + 1e-9f) * exp2f(s0[ra] + s1[ra]);                    \
      float fb = (mk[rb >> 2][rb & 3] + 1e-9f) * exp2f(s0[rb] + s1[rb]);                    \
      dn += fa + fb;                                                                        \
      wds[u] = pack2(fa, fb);                                                               \
    }                                                                                       \
    unsigned e0 = __shfl_xor(h ? wds[0] : wds[2], 32, 64);                                  \
    unsigned e1 = __shfl_xor(h ? wds[1] : wds[3], 32, 64);                                  \
    unsigned e2 = __shfl_xor(h ? wds[4] : wds[6], 32, 64);                                  \
    unsigned e3 = __shfl_xor(h ? wds[5] : wds[7], 32, 64);                                  \
    u32x4 b1u = { h ? e0 : wds[0], h ? e1 : wds[1], h ? wds[2] : e0, h ? wds[3] : e1 };     \
    u32x4 b2u = { h ? e2 : wds[4], h ? e3 : wds[5], h ? wds[6] : e2, h ? wds[7] : e3 };     \
    bf16x8 b1 = __builtin_bit_cast(bf16x8, b1u);                                            \
    bf16x8 b2 = __builtin_bit_cast(bf16x8, b2u);                                            \
    const int vsw = (ln >> 1) & 3;                                                          \
    _Pragma("unroll")                                                                       \
    for (int ct = 0; ct < 8; ++ct) {                                                        \
      const short* Vrow = (VS) + (32 * ct + ln) * 32;                                       \
      bf16x8 av1 = *(const bf16x8*)(Vrow + ((h ^ vsw) << 3));                               \
      bf16x8 av2 = *(const bf16x8*)(Vrow + (((2 + h) ^ vsw) << 3));                         \
      Oacc[ct] = __builtin_amdgcn_mfma_f32_32x32x16_bf16(av1, b1, Oacc[ct], 0, 0, 0);       \
      Oacc[ct] = __builtin_amdgcn_mfma_f32_32x32x16_bf16(av2, b2, Oacc[ct], 0, 0, 0);       \
    }                                                                                       \
  }

// ------------- main fused attention: 256 blocks x 8 waves, parity m-split -----------------
// b = bid&15, l0 = (bid>>4)*128. Wave pair pr = w>>1 owns l in [l0+32pr, +32); parity e = w&1
// processes tiles with index ≡ e (mod 2). Quad-buffered K/V (phase = tile-pair parity).
// One barrier per 2 tiles; epilogue combines pair partials via LDS.
// launch_bounds (512, 1): grid 256 = 1 block/CU anyway; (512,2) capped VGPR at 128 and
// spilled the 128-reg accumulator to scratch (round-5 regression: +30 MiB HBM traffic).
__global__ __launch_bounds__(512, 1) void attn_main(
        const float* __restrict__ Qin,  // [B][C][L] fp32
        const short* __restrict__ Kt,   // [B][L][C] bf16
        const short* __restrict__ Vb,   // [B][C][L] bf16, mask-scaled
        const float* __restrict__ mask, // [B][L]
        float* __restrict__ out) {      // [B][C][L]
    __shared__ __align__(16) char smem[131584];
    // K phase0: [0,32K)  K phase1: [32K,64K)  V phase0: [64K,96K)  V phase1: [96K,128K)
    // (each phase: parity0 tile at +0, parity1 tile at +16K);  Dsh at 128K (512 B)
    float* Dsh = (float*)(smem + 131072);

    const int t = threadIdx.x;
    const int w = t >> 6, lane = t & 63;
    const int ln = lane & 31, h = lane >> 5;
    const int pr = w >> 1, e = w & 1;

    const int b  = blockIdx.x & 15;
    const int l0 = (blockIdx.x >> 4) * 128;
    const int lw = l0 + 32 * pr;                // wave's l base

    const short* Ksrc = Kt + (size_t)b * (L_ * C_);
    const short* Vsrc = Vb + (size_t)b * (C_ * L_);
    const float* mrow = mask + (size_t)b * L_;

    // this wave's compute buffers (parity-selected, wave-uniform)
    short* KsP0 = (short*)smem + e * 8192;
    short* KsP1 = (short*)(smem + 32768) + e * 8192;
    short* VsP0 = (short*)(smem + 65536) + e * 8192;
    short* VsP1 = (short*)(smem + 98304) + e * 8192;
    // staging targets (all 512 threads cooperate)
    short* KsB[2][2] = { {(short*)smem, (short*)(smem + 16384)},
                         {(short*)(smem + 32768), (short*)(smem + 49152)} };
    short* VsB[2][2] = { {(short*)(smem + 65536), (short*)(smem + 81920)},
                         {(short*)(smem + 98304), (short*)(smem + 114688)} };

    // deep prefetch: tiles 0,1 -> phase 0 (lands during Q gather)
    stage_K(Ksrc, KsB[0][0], 0, t);
    stage_K(Ksrc, KsB[0][1], KVB, t);
    stage_V(Vsrc, VsB[0][0], 0, t);
    stage_V(Vsrc, VsB[0][1], KVB, t);

    // Q B-frags: qf[ki] elem (h,j) = Q[c = 16ki+8h+j][l = lw+ln] * CEXP (one-time gather)
    bf16x8 qf[16];
    {
        const float* Qb = Qin + (size_t)b * (C_ * L_) + (lw + ln);
        #pragma unroll
        for (int ki = 0; ki < 16; ++ki) {
            bf16x8 v;
            #pragma unroll
            for (int j = 0; j < 8; ++j) {
                float f = Qb[(size_t)(16 * ki + 8 * h + j) * L_];
                v[j] = f2bf_rne(f * CEXP);
            }
            qf[ki] = v;
        }
    }

    const f32x16 z16 = {0.f,0.f,0.f,0.f,0.f,0.f,0.f,0.f,0.f,0.f,0.f,0.f,0.f,0.f,0.f,0.f};
    f32x16 Oacc[8];
    #pragma unroll
    for (int ct = 0; ct < 8; ++ct) Oacc[ct] = z16;
    float dn = 0.f;

    __syncthreads();   // phase-0 tiles landed

    #pragma unroll 1
    for (int it4 = 0; it4 < NT / 4; ++it4) {
        const int m0 = it4 * (4 * KVB);

        // phase 0: compute tiles m0 + 32e; stage tiles m0+64, m0+96 -> phase 1
        stage_K(Ksrc, KsB[1][0], m0 + 2 * KVB, t);
        stage_K(Ksrc, KsB[1][1], m0 + 3 * KVB, t);
        stage_V(Vsrc, VsB[1][0], m0 + 2 * KVB, t);
        stage_V(Vsrc, VsB[1][1], m0 + 3 * KVB, t);
        TILE_BODY(KsP0, VsP0, m0 + KVB * e)
        __syncthreads();

        // phase 1: compute tiles m0+64+32e; stage tiles m0+128, m0+160 -> phase 0
        if (it4 + 1 < NT / 4) {
            stage_K(Ksrc, KsB[0][0], m0 + 4 * KVB, t);
            stage_K(Ksrc, KsB[0][1], m0 + 5 * KVB, t);
            stage_V(Vsrc, VsB[0][0], m0 + 4 * KVB, t);
            stage_V(Vsrc, VsB[0][1], m0 + 5 * KVB, t);
        }
        TILE_BODY(KsP1, VsP1, m0 + 2 * KVB + KVB * e)
        __syncthreads();
    }

    // ---- combine pair partials: odd waves dump to LDS (dead K/V space), even waves finish
    dn += __shfl_xor(dn, 32, 64);

    if (e) {
        char* Ob = smem + pr * 32768;
        #pragma unroll
        for (int ct = 0; ct < 8; ++ct)
            #pragma unroll
            for (int rq = 0; rq < 4; ++rq) {
                float4 v4 = { Oacc[ct][4*rq+0], Oacc[ct][4*rq+1],
                              Oacc[ct][4*rq+2], Oacc[ct][4*rq+3] };
                *(float4*)(Ob + lane * 512 + (((ct * 4 + rq) ^ (lane & 31)) << 4)) = v4;
            }
        if (h == 0) Dsh[pr * 32 + ln] = dn;
    }
    __syncthreads();
    if (!e) {
        dn += Dsh[pr * 32 + ln];
        const float rden = 1.0f / dn;
        const char* Ob = smem + pr * 32768;
        float* ob = out + (size_t)b * (C_ * L_) + lw + ln;
        #pragma unroll
        for (int ct = 0; ct < 8; ++ct)
            #pragma unroll
            for (int rq = 0; rq < 4; ++rq) {
                float4 p4 = *(const float4*)(Ob + lane * 512 + (((ct * 4 + rq) ^ (lane & 31)) << 4));
                #pragma unroll
                for (int j = 0; j < 4; ++j) {
                    int r = 4 * rq + j;
                    int c = 32 * ct + (r & 3) + 8 * (r >> 2) + 4 * h;
                    ob[(size_t)c * L_] = (Oacc[ct][r] + ((const float*)&p4)[j]) * rden;
                }
            }
    }
}

extern "C" void kernel_launch(void* const* d_in, const int* in_sizes, int n_in,
                              void* d_out, int out_size, void* d_ws, size_t ws_size,
                              hipStream_t stream) {
    const float* Q    = (const float*)d_in[0];
    const float* K    = (const float*)d_in[1];
    const float* V    = (const float*)d_in[2];
    const float* mask = (const float*)d_in[3];
    float* out = (float*)d_out;

    // workspace: Kt | Vb, each B*L*C bf16 = 16 MiB
    short* Kt = (short*)d_ws;
    short* Vb = Kt + (size_t)B_ * L_ * C_;

    prepass_kernel<<<4608, 256, 0, stream>>>(K, V, mask, Kt, Vb);
    attn_main<<<256, 512, 0, stream>>>(Q, Kt, Vb, mask, out);
}

// Round 7
// 235.055 us; speedup vs baseline: 1.2477x; 1.2448x over previous
//
#include <hip/hip_runtime.h>
#include <hip/hip_bf16.h>

#define B_ 16
#define C_ 256
#define L_ 2048
#define KVB 32              // m-tile per iteration
#define NT (L_ / KVB)       // 64 tiles

typedef __attribute__((ext_vector_type(8))) short bf16x8;
typedef __attribute__((ext_vector_type(4))) unsigned u32x4;
typedef __attribute__((ext_vector_type(16))) float f32x16;

#define CEXP 0.09016844005556021f   // (1/16) * log2(e), folded into Q conversion

// round-to-nearest-even float -> bf16
__device__ __forceinline__ short f2bf_rne(float f) {
    union { float f; unsigned u; } x; x.f = f;
    unsigned r = x.u + 0x7fffu + ((x.u >> 16) & 1u);
    return (short)(r >> 16);
}

__device__ __forceinline__ unsigned pack2(float lo, float hi) {
    return (unsigned)(unsigned short)f2bf_rne(lo)
         | ((unsigned)(unsigned short)f2bf_rne(hi) << 16);
}

// direct global->LDS DMA, 16 bytes per lane; LDS dest = wave-uniform base + lane*16
__device__ __forceinline__ void gld_lds16(const void* g, void* l) {
    __builtin_amdgcn_global_load_lds(
        (const __attribute__((address_space(1))) void*)g,
        (__attribute__((address_space(3))) void*)l, 16, 0, 0);
}

// ---------------- prepass: K transpose+cvt (blocks 0..511), V*mask cvt (512..4607) ----------
// K-transpose rewritten (round 7): per thread, 8 coalesced dword loads along l for one
// (l, 8-c chunk) -> 1 ds_write_b128 at phys chunk ck^(l&31) (conflict-free: per 8-lane
// phase, l&31 spans 8 consecutive values -> all 8 bank-quads). Replaces 64 scalar
// ds_write_u16/thread (the ~100 us prepass cost). Read side unchanged.
__global__ __launch_bounds__(256) void prepass_kernel(
        const float* __restrict__ Kin, const float* __restrict__ Vin,
        const float* __restrict__ mask,
        short* __restrict__ Kt, short* __restrict__ Vb) {
    const int bid = blockIdx.x;
    const int t = threadIdx.x;
    if (bid < 512) {
        __shared__ unsigned short tile[64 * 256];   // 32 KB; phys 16B-chunk = ck ^ (l&31)
        const int b  = bid >> 5;
        const int l0 = (bid & 31) * 64;
        #pragma unroll
        for (int iter = 0; iter < 8; ++iter) {
            int l  = t & 63;                       // 0..63
            int ck = (t >> 6) + 4 * iter;          // 0..31 (8-c chunk)
            const float* src = Kin + ((size_t)(b * C_ + 8 * ck)) * L_ + l0 + l;
            unsigned pk[4];
            #pragma unroll
            for (int jj = 0; jj < 4; ++jj) {
                float f0 = src[(size_t)(2 * jj) * L_];
                float f1 = src[(size_t)(2 * jj + 1) * L_];
                pk[jj] = pack2(f0, f1);
            }
            uint4 o = {pk[0], pk[1], pk[2], pk[3]};
            *(uint4*)(tile + l * 256 + ((ck ^ (l & 31)) << 3)) = o;
        }
        __syncthreads();
        #pragma unroll
        for (int iter = 0; iter < 8; ++iter) {
            int li = iter * 8 + (t >> 5);          // 0..63
            int ck = t & 31;                       // logical 16-B chunk
            uint4 val = *(const uint4*)(tile + li * 256 + ((ck ^ (li & 31)) << 3));
            *(uint4*)(Kt + ((size_t)(b * L_ + l0 + li)) * C_ + ck * 8) = val;
        }
    } else {
        // 4096 blocks x 256 threads x 8 elems = B_*C_*L_
        size_t e = ((size_t)(bid - 512) * 256 + t) * 8;
        int b = (int)(e >> 19);
        int m = (int)(e & (L_ - 1));
        const float4 v0 = *(const float4*)(Vin + e);
        const float4 v1 = *(const float4*)(Vin + e + 4);
        const float* mp = mask + ((size_t)b << 11) + m;
        const float4 m0 = *(const float4*)mp;
        const float4 m1 = *(const float4*)(mp + 4);
        uint4 o;
        o.x = pack2(v0.x * m0.x, v0.y * m0.y);
        o.y = pack2(v0.z * m0.z, v0.w * m0.w);
        o.z = pack2(v1.x * m1.x, v1.y * m1.y);
        o.w = pack2(v1.z * m1.z, v1.w * m1.w);
        *(uint4*)(Vb + e) = o;
    }
}

// ---- stage one 32-row K tile via DMA; XOR swizzle on the GLOBAL side ----
// K LDS: [m 0..31][slot p 0..31 of 16B]; phys slot p holds global chunk p ^ m.
__device__ __forceinline__ void stage_K(const short* __restrict__ Ksrc,
                                        short* Ks, int m0, int t) {
    #pragma unroll
    for (int rr = 0; rr < 4; ++rr) {
        int G = rr * 256 + t;                  // 0..1023
        int m = G >> 5, p = G & 31;
        gld_lds16(Ksrc + ((size_t)(m0 + m) << 8) + ((p ^ m) << 3), Ks + G * 8);
    }
}

// ---- stage one V tile (256 c x 32 m bf16 = 16 KB) via DMA ----
// V LDS: [c 0..255][slot p 0..3 of 16B]; phys slot p holds global chunk p ^ ((c>>1)&3).
// Bank check (round-5 fix): read quad(lane) = 4*(ln&1) + (h ^ ((ln>>1)&3)) -> bijection
// over 8 quads per 8 consecutive lanes -> conflict-free ds_read_b128.
__device__ __forceinline__ void stage_V(const short* __restrict__ Vsrc,
                                        short* Vs, int m0, int t) {
    #pragma unroll
    for (int rr = 0; rr < 4; ++rr) {
        int G = rr * 256 + t;                  // 0..1023
        int c = G >> 2, p = G & 3;
        gld_lds16(Vsrc + (size_t)c * L_ + m0 + ((p ^ ((c >> 1) & 3)) << 3), Vs + G * 8);
    }
}

// ---- per-tile body ----
// S' = mfma(A=K, B=Q): lane (ln,h) holds S'[m0 + mr(r,h)][l = lw+ln], mr(r,h)=(r&3)+8(r>>2)+4h.
// softmax lane-local; P redistributed across h-halves via 4 shfl_xor into B-frags b1,b2;
// O = mfma(A=V from LDS, B=P): D[row=c][col=l], 1 contiguous 16-B V chunk per lane per MFMA.
#define TILE_BODY(KS, VS, M0)                                                               \
  {                                                                                         \
    const short* Krow = (KS) + ln * 256;                                                    \
    bf16x8 kf[16];                                                                          \
    _Pragma("unroll")                                                                       \
    for (int ki = 0; ki < 16; ++ki)                                                         \
      kf[ki] = *(const bf16x8*)(Krow + (((2 * ki + h) ^ ln) << 3));                         \
    float4 mk[4];                                                                           \
    _Pragma("unroll")                                                                       \
    for (int s = 0; s < 4; ++s) mk[s] = *(const float4*)(mrow + (M0) + 8 * s + 4 * h);      \
    f32x16 s0 = z16, s1 = z16;                                                              \
    _Pragma("unroll")                                                                       \
    for (int ki = 0; ki < 8; ++ki)                                                          \
      s0 = __builtin_amdgcn_mfma_f32_32x32x16_bf16(kf[ki], qf[ki], s0, 0, 0, 0);            \
    _Pragma("unroll")                                                                       \
    for (int ki = 8; ki < 16; ++ki)                                                         \
      s1 = __builtin_amdgcn_mfma_f32_32x32x16_bf16(kf[ki], qf[ki], s1, 0, 0, 0);            \
    unsigned wds[8];                                                                        \
    _Pragma("unroll")                                                                       \
    for (int u = 0; u < 8; ++u) {                                                           \
      const int ra = 2 * u, rb = 2 * u + 1;                                                 \
      float fa = (mk[ra >> 2][ra & 3] + 1e-9f) * exp2f(s0[ra] + s1[ra]);                    \
      float fb = (mk[rb >> 2][rb & 3] + 1e-9f) * exp2f(s0[rb] + s1[rb]);                    \
      dn += fa + fb;                                                                        \
      wds[u] = pack2(fa, fb);                                                               \
    }                                                                                       \
    unsigned e0 = __shfl_xor(h ? wds[0] : wds[2], 32, 64);                                  \
    unsigned e1 = __shfl_xor(h ? wds[1] : wds[3], 32, 64);                                  \
    unsigned e2 = __shfl_xor(h ? wds[4] : wds[6], 32, 64);                                  \
    unsigned e3 = __shfl_xor(h ? wds[5] : wds[7], 32, 64);                                  \
    u32x4 b1u = { h ? e0 : wds[0], h ? e1 : wds[1], h ? wds[2] : e0, h ? wds[3] : e1 };     \
    u32x4 b2u = { h ? e2 : wds[4], h ? e3 : wds[5], h ? wds[6] : e2, h ? wds[7] : e3 };     \
    bf16x8 b1 = __builtin_bit_cast(bf16x8, b1u);                                            \
    bf16x8 b2 = __builtin_bit_cast(bf16x8, b2u);                                            \
    const int vsw = (ln >> 1) & 3;                                                          \
    _Pragma("unroll")                                                                       \
    for (int ct = 0; ct < 8; ++ct) {                                                        \
      const short* Vrow = (VS) + (32 * ct + ln) * 32;                                       \
      bf16x8 av1 = *(const bf16x8*)(Vrow + ((h ^ vsw) << 3));                               \
      bf16x8 av2 = *(const bf16x8*)(Vrow + (((2 + h) ^ vsw) << 3));                         \
      Oacc[ct] = __builtin_amdgcn_mfma_f32_32x32x16_bf16(av1, b1, Oacc[ct], 0, 0, 0);       \
      Oacc[ct] = __builtin_amdgcn_mfma_f32_32x32x16_bf16(av2, b2, Oacc[ct], 0, 0, 0);       \
    }                                                                                       \
  }

// ---------------- main fused attention: 256 blocks x 4 waves, wave owns 32 l-rows ---------
// b = bid&15 (same-batch blocks cluster per XCD), l0 = (bid>>4)*128; wave w: l in [l0+32w, +32).
// 256-thread blocks: compiler honors ~208 VGPR (rounds 5/6 showed 512-thread blocks are
// force-capped at 128 VGPR -> accumulator spills). All cross-barrier VMEM is DMA issued a
// full iteration ahead.
__global__ __launch_bounds__(256, 1) void attn_main(
        const float* __restrict__ Qin,  // [B][C][L] fp32
        const short* __restrict__ Kt,   // [B][L][C] bf16
        const short* __restrict__ Vb,   // [B][C][L] bf16, mask-scaled
        const float* __restrict__ mask, // [B][L]
        float* __restrict__ out) {      // [B][C][L]
    __shared__ __align__(16) char smem[65536];
    short* KsB0 = (short*)smem;                 // 16 KB (even tiles)
    short* KsB1 = (short*)(smem + 16384);       // 16 KB (odd tiles)
    short* VsB0 = (short*)(smem + 32768);       // 16 KB (even tiles)
    short* VsB1 = (short*)(smem + 49152);       // 16 KB (odd tiles)

    const int t = threadIdx.x;
    const int w = t >> 6, lane = t & 63;
    const int ln = lane & 31, h = lane >> 5;

    const int b  = blockIdx.x & 15;
    const int l0 = (blockIdx.x >> 4) * 128;
    const int lw = l0 + 32 * w;                 // wave's l base

    const short* Ksrc = Kt + (size_t)b * (L_ * C_);
    const short* Vsrc = Vb + (size_t)b * (C_ * L_);
    const float* mrow = mask + (size_t)b * L_;

    // deep prefetch: tile 0 (lands during Q gather)
    stage_K(Ksrc, KsB0, 0, t);
    stage_V(Vsrc, VsB0, 0, t);

    // Q B-frags: qf[ki] elem (h,j) = Q[c = 16ki+8h+j][l = lw+ln] * CEXP (one-time gather)
    bf16x8 qf[16];
    {
        const float* Qb = Qin + (size_t)b * (C_ * L_) + (lw + ln);
        #pragma unroll
        for (int ki = 0; ki < 16; ++ki) {
            bf16x8 v;
            #pragma unroll
            for (int j = 0; j < 8; ++j) {
                float f = Qb[(size_t)(16 * ki + 8 * h + j) * L_];
                v[j] = f2bf_rne(f * CEXP);
            }
            qf[ki] = v;
        }
    }

    const f32x16 z16 = {0.f,0.f,0.f,0.f,0.f,0.f,0.f,0.f,0.f,0.f,0.f,0.f,0.f,0.f,0.f,0.f};
    f32x16 Oacc[8];
    #pragma unroll
    for (int ct = 0; ct < 8; ++ct) Oacc[ct] = z16;
    float dn = 0.f;

    __syncthreads();   // tile 0 landed

    #pragma unroll 1
    for (int it2 = 0; it2 < NT / 2; ++it2) {
        const int m0a = it2 * (2 * KVB);
        const int m0b = m0a + KVB;

        // even tile: compute from B0, prefetch m0b -> B1
        stage_K(Ksrc, KsB1, m0b, t);
        stage_V(Vsrc, VsB1, m0b, t);
        TILE_BODY(KsB0, VsB0, m0a)
        __syncthreads();

        // odd tile: compute from B1, prefetch m0b+KVB -> B0
        if (m0b + KVB < L_) {
            stage_K(Ksrc, KsB0, m0b + KVB, t);
            stage_V(Vsrc, VsB0, m0b + KVB, t);
        }
        TILE_BODY(KsB1, VsB1, m0b)
        __syncthreads();
    }

    // ---- denominator: one cross-half exchange -> every lane holds full denom for l=lw+ln
    dn += __shfl_xor(dn, 32, 64);
    const float rden = 1.0f / dn;

    // ---- stores: D[row=c][col=l=ln]; per (ct,r) lanes are 2 x 128-B contiguous segments
    float* ob = out + (size_t)b * (C_ * L_) + lw + ln;
    #pragma unroll
    for (int ct = 0; ct < 8; ++ct)
        #pragma unroll
        for (int r = 0; r < 16; ++r) {
            int c = 32 * ct + (r & 3) + 8 * (r >> 2) + 4 * h;
            ob[(size_t)c * L_] = Oacc[ct][r] * rden;
        }
}

extern "C" void kernel_launch(void* const* d_in, const int* in_sizes, int n_in,
                              void* d_out, int out_size, void* d_ws, size_t ws_size,
                              hipStream_t stream) {
    const float* Q    = (const float*)d_in[0];
    const float* K    = (const float*)d_in[1];
    const float* V    = (const float*)d_in[2];
    const float* mask = (const float*)d_in[3];
    float* out = (float*)d_out;

    // workspace: Kt | Vb, each B*L*C bf16 = 16 MiB
    short* Kt = (short*)d_ws;
    short* Vb = Kt + (size_t)B_ * L_ * C_;

    prepass_kernel<<<4608, 256, 0, stream>>>(K, V, mask, Kt, Vb);
    attn_main<<<256, 256, 0, stream>>>(Q, Kt, Vb, mask, out);
}